// Round 1
// baseline (1253.991 us; speedup 1.0000x reference)
//
#include <hip/hip_runtime.h>
#include <math.h>

#define D128 128
#define NH 8
#define DK16 16
#define NT 4
#define MAXLEN 240

__device__ __forceinline__ void atomicMaxF(float* addr, float v) {
    if (v >= 0.f) atomicMax((int*)addr, __float_as_int(v));
    else          atomicMin((unsigned int*)addr, __float_as_uint(v));
}

__global__ void init_kernel(float* mmax, float* den, float* aggr, int n8, int n128) {
    int i = blockIdx.x * blockDim.x + threadIdx.x;
    int stride = gridDim.x * blockDim.x;
    for (int j = i; j < n8; j += stride) { mmax[j] = -INFINITY; den[j] = 0.f; }
    for (int j = i; j < n128; j += stride) aggr[j] = 0.f;
}

// rte_out[m,d] = sum_i emb[m,i] * rte_W[i,d] + rte_b[d]
__global__ void rte_out_kernel(const float* __restrict__ rte_W, const float* __restrict__ rte_b,
                               float* __restrict__ rte_out) {
    int m = blockIdx.x, d = threadIdx.x;
    __shared__ float emb[D128];
    int j2 = d & ~1;
    float div = expf((float)j2 * (-9.210340371976184f / 128.f));  // -ln(10000)/128
    float ang = (float)m * div;
    float val = ((d & 1) ? cosf(ang) : sinf(ang)) * 0.08838834764831845f;  // 1/sqrt(128)
    emb[d] = val;
    __syncthreads();
    float acc = rte_b[d];
    #pragma unroll 8
    for (int i = 0; i < D128; ++i) acc += emb[i] * rte_W[i * D128 + d];
    rte_out[m * D128 + d] = acc;
}

// k_rte[t,m,d] = sum_i rte_out[m,i] * Wk[t,i,d]   (z=0 -> Wk/k_rte, z=1 -> Wv/v_rte)
__global__ void rte_proj_kernel(const float* __restrict__ rte_out,
                                const float* __restrict__ Wk, const float* __restrict__ Wv,
                                float* __restrict__ k_rte, float* __restrict__ v_rte) {
    int m = blockIdx.x, t = blockIdx.y, z = blockIdx.z, d = threadIdx.x;
    __shared__ float sr[D128];
    sr[d] = rte_out[m * D128 + d];
    __syncthreads();
    const float* W = (z == 0 ? Wk : Wv) + t * D128 * D128;
    float acc = 0.f;
    #pragma unroll 8
    for (int i = 0; i < D128; ++i) acc += sr[i] * W[i * D128 + d];
    float* dst = (z == 0 ? k_rte : v_rte);
    dst[(t * MAXLEN + m) * D128 + d] = acc;
}

__global__ void node_kqv_kernel(const float* __restrict__ x, const int* __restrict__ ntype,
                                const float* __restrict__ Wk, const float* __restrict__ bk,
                                const float* __restrict__ Wq, const float* __restrict__ bq,
                                const float* __restrict__ Wv, const float* __restrict__ bv,
                                float* __restrict__ kn, float* __restrict__ qn,
                                float* __restrict__ vn, int N) {
    int n = blockIdx.x, d = threadIdx.x;
    __shared__ float sx[D128];
    sx[d] = x[(size_t)n * D128 + d];
    __syncthreads();
    int t = ntype[n];
    const float* wk = Wk + t * D128 * D128;
    const float* wq = Wq + t * D128 * D128;
    const float* wv = Wv + t * D128 * D128;
    float ak = bk[t * D128 + d], aq = bq[t * D128 + d], av = bv[t * D128 + d];
    #pragma unroll 4
    for (int i = 0; i < D128; ++i) {
        float xv = sx[i];
        ak += xv * wk[i * D128 + d];
        aq += xv * wq[i * D128 + d];
        av += xv * wv[i * D128 + d];
    }
    kn[(size_t)n * D128 + d] = ak;
    qn[(size_t)n * D128 + d] = aq;
    vn[(size_t)n * D128 + d] = av;
}

// one edge per 128 threads; 2 edges per 256-thread block
__global__ void edge_logits_kernel(const int* __restrict__ ei, const int* __restrict__ etype,
                                   const int* __restrict__ etime, const int* __restrict__ ntype,
                                   const float* __restrict__ kn, const float* __restrict__ qn,
                                   const float* __restrict__ krte,
                                   const float* __restrict__ rel_att, const float* __restrict__ rel_pri,
                                   float* __restrict__ logits, float* __restrict__ mmax, int E) {
    int sub = threadIdx.x >> 7;
    int d = threadIdx.x & 127;
    int e = blockIdx.x * 2 + sub;
    int ec = e < E ? e : E - 1;
    __shared__ float ske[2][D128];
    int src = ei[ec], tgt = ei[E + ec];
    int r = etype[ec], tm = etime[ec], st = ntype[src];
    ske[sub][d] = kn[(size_t)src * D128 + d] + krte[((st * MAXLEN + tm) * D128) + d];
    __syncthreads();
    int h = d >> 4, kk = d & 15;
    const float* A = rel_att + (r * NH + h) * DK16 * DK16;
    float k2 = 0.f;
    #pragma unroll
    for (int k = 0; k < DK16; ++k) k2 += ske[sub][h * DK16 + k] * A[k * DK16 + kk];
    float p = qn[(size_t)tgt * D128 + d] * k2;
    #pragma unroll
    for (int off = 8; off > 0; off >>= 1) p += __shfl_xor(p, off, 16);
    if (kk == 0 && e < E) {
        float lg = p * rel_pri[r * NH + h] * 0.25f;  // 1/sqrt(16)
        logits[(size_t)e * NH + h] = lg;
        atomicMaxF(&mmax[(size_t)tgt * NH + h], lg);
    }
}

__global__ void edge_exp_kernel(const int* __restrict__ ei, float* __restrict__ logits,
                                const float* __restrict__ mmax, float* __restrict__ den, int E) {
    int i = blockIdx.x * blockDim.x + threadIdx.x;
    if (i >= E * NH) return;
    int e = i >> 3, h = i & 7;
    int tgt = ei[E + e];
    float ex = expf(logits[i] - mmax[(size_t)tgt * NH + h]);
    logits[i] = ex;
    unsafeAtomicAdd(&den[(size_t)tgt * NH + h], ex);
}

__global__ void edge_aggr_kernel(const int* __restrict__ ei, const int* __restrict__ etype,
                                 const int* __restrict__ etime, const int* __restrict__ ntype,
                                 const float* __restrict__ vn, const float* __restrict__ vrte,
                                 const float* __restrict__ rel_msg, const float* __restrict__ ex,
                                 const float* __restrict__ den, float* __restrict__ aggr, int E) {
    int sub = threadIdx.x >> 7;
    int d = threadIdx.x & 127;
    int e = blockIdx.x * 2 + sub;
    int ec = e < E ? e : E - 1;
    __shared__ float sv[2][D128];
    int src = ei[ec], tgt = ei[E + ec];
    int r = etype[ec], tm = etime[ec], st = ntype[src];
    sv[sub][d] = vn[(size_t)src * D128 + d] + vrte[((st * MAXLEN + tm) * D128) + d];
    __syncthreads();
    int h = d >> 4, kk = d & 15;
    const float* Mw = rel_msg + (r * NH + h) * DK16 * DK16;
    float mg = 0.f;
    #pragma unroll
    for (int k = 0; k < DK16; ++k) mg += sv[sub][h * DK16 + k] * Mw[k * DK16 + kk];
    if (e < E) {
        float att = ex[(size_t)e * NH + h] / den[(size_t)tgt * NH + h];
        unsafeAtomicAdd(&aggr[(size_t)tgt * D128 + d], mg * att);
    }
}

__global__ void node_update_kernel(const float* __restrict__ x, const int* __restrict__ ntype,
                                   const float* __restrict__ aggr,
                                   const float* __restrict__ Wa, const float* __restrict__ ba,
                                   const float* __restrict__ gamma, const float* __restrict__ beta,
                                   const float* __restrict__ skip, float* __restrict__ out, int N) {
    int n = blockIdx.x, d = threadIdx.x;
    __shared__ float sa[D128];
    __shared__ float red[4];
    float ag = aggr[(size_t)n * D128 + d];
    float a = 0.5f * ag * (1.f + erff(ag * 0.7071067811865476f));  // exact gelu
    sa[d] = a;
    __syncthreads();
    int t = ntype[n];
    const float* wa = Wa + t * D128 * D128;
    float tr = ba[t * D128 + d];
    #pragma unroll 4
    for (int i = 0; i < D128; ++i) tr += sa[i] * wa[i * D128 + d];
    float alpha = 1.f / (1.f + expf(-skip[t]));
    float hv = tr * alpha + x[(size_t)n * D128 + d] * (1.f - alpha);
    float s1 = hv, s2 = hv * hv;
    #pragma unroll
    for (int off = 32; off > 0; off >>= 1) {
        s1 += __shfl_xor(s1, off, 64);
        s2 += __shfl_xor(s2, off, 64);
    }
    int w = d >> 6;
    if ((d & 63) == 0) { red[w * 2] = s1; red[w * 2 + 1] = s2; }
    __syncthreads();
    float S1 = red[0] + red[2], S2 = red[1] + red[3];
    float mu = S1 * (1.f / 128.f);
    float var = S2 * (1.f / 128.f) - mu * mu;
    float inv = 1.f / sqrtf(var + 1e-5f);
    out[(size_t)n * D128 + d] = (hv - mu) * inv * gamma[t * D128 + d] + beta[t * D128 + d];
}

extern "C" void kernel_launch(void* const* d_in, const int* in_sizes, int n_in,
                              void* d_out, int out_size, void* d_ws, size_t ws_size,
                              hipStream_t stream) {
    const float* node_inp = (const float*)d_in[0];
    const int*   node_type = (const int*)d_in[1];
    const int*   edge_index = (const int*)d_in[2];
    const int*   edge_type = (const int*)d_in[3];
    const int*   edge_time = (const int*)d_in[4];
    const float* Wk = (const float*)d_in[5];
    const float* bk = (const float*)d_in[6];
    const float* Wq = (const float*)d_in[7];
    const float* bq = (const float*)d_in[8];
    const float* Wv = (const float*)d_in[9];
    const float* bv = (const float*)d_in[10];
    const float* Wa = (const float*)d_in[11];
    const float* ba = (const float*)d_in[12];
    const float* gamma = (const float*)d_in[13];
    const float* beta = (const float*)d_in[14];
    const float* rel_pri = (const float*)d_in[15];
    const float* rel_att = (const float*)d_in[16];
    const float* rel_msg = (const float*)d_in[17];
    const float* skip = (const float*)d_in[18];
    const float* rte_W = (const float*)d_in[19];
    const float* rte_b = (const float*)d_in[20];

    int N = in_sizes[0] / D128;
    int E = in_sizes[3];

    float* ws = (float*)d_ws;
    float* rte_out = ws;                                   // 240*128
    float* k_rte  = rte_out + MAXLEN * D128;               // 4*240*128
    float* v_rte  = k_rte + NT * MAXLEN * D128;            // 4*240*128
    float* k_node = v_rte + NT * MAXLEN * D128;            // N*128
    float* q_node = k_node + (size_t)N * D128;
    float* v_node = q_node + (size_t)N * D128;
    float* logits = v_node + (size_t)N * D128;             // E*8
    float* mmax   = logits + (size_t)E * NH;               // N*8
    float* den    = mmax + (size_t)N * NH;                 // N*8
    float* aggr   = den + (size_t)N * NH;                  // N*128

    init_kernel<<<1024, 256, 0, stream>>>(mmax, den, aggr, N * NH, N * D128);
    rte_out_kernel<<<MAXLEN, D128, 0, stream>>>(rte_W, rte_b, rte_out);
    dim3 g2(MAXLEN, NT, 2);
    rte_proj_kernel<<<g2, D128, 0, stream>>>(rte_out, Wk, Wv, k_rte, v_rte);
    node_kqv_kernel<<<N, D128, 0, stream>>>(node_inp, node_type, Wk, bk, Wq, bq, Wv, bv,
                                            k_node, q_node, v_node, N);
    edge_logits_kernel<<<(E + 1) / 2, 256, 0, stream>>>(edge_index, edge_type, edge_time, node_type,
                                                        k_node, q_node, k_rte, rel_att, rel_pri,
                                                        logits, mmax, E);
    edge_exp_kernel<<<(E * NH + 255) / 256, 256, 0, stream>>>(edge_index, logits, mmax, den, E);
    edge_aggr_kernel<<<(E + 1) / 2, 256, 0, stream>>>(edge_index, edge_type, edge_time, node_type,
                                                      v_node, v_rte, rel_msg, logits, den, aggr, E);
    node_update_kernel<<<N, D128, 0, stream>>>(node_inp, node_type, aggr, Wa, ba, gamma, beta,
                                               skip, (float*)d_out, N);
}